// Round 2
// baseline (3434.741 us; speedup 1.0000x reference)
//
#include <hip/hip_runtime.h>
#include <hip/hip_cooperative_groups.h>

namespace cg = cooperative_groups;

// Problem dims
#define DD    512
#define CC    256
#define UU    40
#define TT    16
#define BB    64
#define PP    (DD * CC)        // 131072
#define NT    512              // threads per block
#define NB    256              // blocks (= #CUs, 1 block/CU)

__device__ __forceinline__ float hsig(float x) {
    // keras hard_sigmoid: clip(0.2x + 0.5, 0, 1)
    return fminf(fmaxf(fmaf(0.2f, x, 0.5f), 0.f), 1.f);
}

__device__ __forceinline__ float ftanh(float x) {
    float xc = fminf(fmaxf(x, -15.f), 15.f);
    float e  = __expf(2.f * xc);
    return (e - 1.f) / (e + 1.f);
}

__device__ __forceinline__ float4 ld4(const float* p) {
    return *reinterpret_cast<const float4*>(p);
}

// az[0..39] = bias[go..] + inp@Wk[:,go..] + h@Wr[:,go..]   (all LDS reads wave-uniform)
__device__ __forceinline__ void gate_z(const float* __restrict__ sWk,
                                       const float* __restrict__ sWr,
                                       const float* __restrict__ sB,
                                       const float (&h)[UU],
                                       const float (&inp)[5],
                                       int go, float (&az)[UU])
{
#pragma unroll
    for (int j = 0; j < 10; ++j) {
        float4 b4 = ld4(sB + go + 4 * j);
        az[4*j+0] = b4.x; az[4*j+1] = b4.y; az[4*j+2] = b4.z; az[4*j+3] = b4.w;
    }
#pragma unroll
    for (int k = 0; k < 5; ++k) {
        float v = inp[k];
#pragma unroll
        for (int j = 0; j < 10; ++j) {
            float4 w = ld4(sWk + k * 160 + go + 4 * j);
            az[4*j+0] = fmaf(v, w.x, az[4*j+0]);
            az[4*j+1] = fmaf(v, w.y, az[4*j+1]);
            az[4*j+2] = fmaf(v, w.z, az[4*j+2]);
            az[4*j+3] = fmaf(v, w.w, az[4*j+3]);
        }
    }
#pragma unroll
    for (int u = 0; u < UU; ++u) {
        float hu = h[u];
#pragma unroll
        for (int j = 0; j < 10; ++j) {
            float4 w = ld4(sWr + u * 160 + go + 4 * j);
            az[4*j+0] = fmaf(hu, w.x, az[4*j+0]);
            az[4*j+1] = fmaf(hu, w.y, az[4*j+1]);
            az[4*j+2] = fmaf(hu, w.z, az[4*j+2]);
            az[4*j+3] = fmaf(hu, w.w, az[4*j+3]);
        }
    }
}

__global__ void __launch_bounds__(NT, 2)
meta_kernel(const float* __restrict__ feats,   // [T][B][D]
            const float* __restrict__ labels,  // [T][B][C]
            const float* __restrict__ params,  // [P]
            const float* __restrict__ gWk,     // [4][5][160]
            const float* __restrict__ gWr,     // [4][40][160]
            const float* __restrict__ gB,      // [4][160]
            const float* __restrict__ gWf,     // [4][41]
            const float* __restrict__ gbf,     // [4]
            const float* __restrict__ gWi,     // [4][41]
            const float* __restrict__ gbi,     // [4]
            float* __restrict__ out,           // [P]
            float* __restrict__ pbuf,          // ws: [P]
            float* __restrict__ gbuf,          // ws: [P]
            float* __restrict__ loss_acc)      // ws: [T]
{
    __shared__ __align__(16) float sWr[UU * 160];   // 6400
    __shared__ __align__(16) float sWk[5 * 160];    // 800
    __shared__ __align__(16) float sB[160];
    __shared__ __align__(16) float sWf[41];
    __shared__ __align__(16) float sWi[41];
    __shared__ float sSc[2];
    __shared__ float sR[BB * 8];                    // residual tile [b][ccl]
    __shared__ float sRed[8];

    const int tid = threadIdx.x;
    const int blk = blockIdx.x;
    // param = blk*512 + tid ; d = param>>8 ; group boundaries at d = 64/192/384
    const int gi = (blk < 32) ? 0 : (blk < 96) ? 1 : (blk < 192) ? 2 : 3;

    for (int i = tid; i < UU * 160; i += NT) sWr[i] = gWr[gi * UU * 160 + i];
    for (int i = tid; i < 800;      i += NT) sWk[i] = gWk[gi * 800 + i];
    if (tid < 160) sB[tid] = gB[gi * 160 + tid];
    if (tid < 41) { sWf[tid] = gWf[gi * 41 + tid]; sWi[tid] = gWi[gi * 41 + tid]; }
    if (tid == 0) { sSc[0] = gbf[gi]; sSc[1] = gbi[gi]; }

    const int param = blk * NT + tid;
    float p = params[param];
    pbuf[param] = p;
    if (blk == 0 && tid < TT) loss_acc[tid] = 0.f;   // ws is poisoned each launch

    float h[UU], c[UU];
#pragma unroll
    for (int u = 0; u < UU; ++u) { h[u] = 0.f; c[u] = 0.f; }
    float fprev = 0.f, iprev = 0.f;
    __syncthreads();

    cg::grid_group grid = cg::this_grid();

    const float negExpP = 4.5399929762484854e-05f;   // e^-10
    const float expP    = 22026.465794806718f;       // e^10

#pragma unroll 1
    for (int t = 0; t < TT; ++t) {
        grid.sync();   // pbuf (and loss zeros) visible everywhere

        // ---- Phase A (blocks 0..31): residual slice, loss, grad slice ----
        if (blk < 32) {
            const int b   = tid >> 3;            // 0..63
            const int ccl = tid & 7;
            const int cc  = blk * 8 + ccl;       // this block owns 8 C-columns
            const float* frow = feats + (size_t)(t * BB + b) * DD;
            float acc = 0.f;
#pragma unroll 8
            for (int d = 0; d < DD; ++d)
                acc = fmaf(frow[d], pbuf[d * CC + cc], acc);
            float r = labels[(size_t)(t * BB + b) * CC + cc] - acc;
            sR[tid] = r;                          // [b][ccl]
            float r2 = r * r;
#pragma unroll
            for (int off = 32; off > 0; off >>= 1) r2 += __shfl_down(r2, off);
            if ((tid & 63) == 0) sRed[tid >> 6] = r2;
            __syncthreads();
            if (tid == 0) {
                float s = 0.f;
#pragma unroll
                for (int w = 0; w < 8; ++w) s += sRed[w];
                atomicAdd(&loss_acc[t], s);
            }
            // grad slice: d = tid, 8 columns; g = -2/16384 * sum_b f[b,d] r[b,cc]
            float gk[8];
#pragma unroll
            for (int k = 0; k < 8; ++k) gk[k] = 0.f;
            const float* fcol = feats + (size_t)t * BB * DD + tid;
#pragma unroll 4
            for (int b2 = 0; b2 < BB; ++b2) {
                float fv = fcol[b2 * DD];
#pragma unroll
                for (int k = 0; k < 8; ++k) gk[k] = fmaf(fv, sR[b2 * 8 + k], gk[k]);
            }
#pragma unroll
            for (int k = 0; k < 8; ++k)
                gbuf[tid * CC + blk * 8 + k] = gk[k] * (-1.220703125e-4f); // -2/16384
        }
        grid.sync();   // gbuf + loss visible

        // ---- Phase B (all blocks): preprocess + LSTM + param update ----
        float loss = loss_acc[t] * (1.f / 16384.f);
        float g = gbuf[param];

        float ag  = fabsf(g);
        bool  m1g = ag > negExpP;
        float sgn = (g > 0.f) ? 1.f : ((g < 0.f) ? -1.f : 0.f);
        float g0  = m1g ? (logf(ag) * 0.1f) : -1.f;
        float g1  = m1g ? sgn : (expP * g);
        bool  m1l = loss > negExpP;
        float l0  = m1l ? (logf(loss) * 0.1f) : -1.f;
        float l1  = m1l ? 1.f : (expP * loss);

        float inp[5] = { p, g0, g1, l0, l1 };
        float az[UU], ig[UU];

        gate_z(sWk, sWr, sB, h, inp, 0, az);     // i gate
#pragma unroll
        for (int j = 0; j < UU; ++j) ig[j] = hsig(az[j]);
        gate_z(sWk, sWr, sB, h, inp, 40, az);    // f gate
#pragma unroll
        for (int j = 0; j < UU; ++j) c[j] *= hsig(az[j]);
        gate_z(sWk, sWr, sB, h, inp, 80, az);    // cbar
#pragma unroll
        for (int j = 0; j < UU; ++j) c[j] = fmaf(ig[j], ftanh(az[j]), c[j]);
        gate_z(sWk, sWr, sB, h, inp, 120, az);   // o gate
        float fdot = 0.f, idot = 0.f;
#pragma unroll
        for (int j = 0; j < UU; ++j) {
            float hn = hsig(az[j]) * ftanh(c[j]);
            h[j] = hn;
            fdot = fmaf(hn, sWf[j], fdot);
            idot = fmaf(hn, sWi[j], idot);
        }
        float fnew = fmaxf(fmaf(fprev, sWf[UU], fdot) + sSc[0], 0.f);
        float inew = fmaxf(fmaf(iprev, sWi[UU], idot) + sSc[1], 0.f);

        p = fmaf(fnew, p, -(inew * g));
        fprev = fnew; iprev = inew;
        pbuf[param] = p;
    }

    out[param] = p;
}

extern "C" void kernel_launch(void* const* d_in, const int* in_sizes, int n_in,
                              void* d_out, int out_size, void* d_ws, size_t ws_size,
                              hipStream_t stream) {
    const float* feats  = (const float*)d_in[0];
    const float* labels = (const float*)d_in[1];
    const float* params = (const float*)d_in[2];
    const float* gWk    = (const float*)d_in[3];
    const float* gWr    = (const float*)d_in[4];
    const float* gB     = (const float*)d_in[5];
    const float* gWf    = (const float*)d_in[6];
    const float* gbf    = (const float*)d_in[7];
    const float* gWi    = (const float*)d_in[8];
    const float* gbi    = (const float*)d_in[9];
    float* out  = (float*)d_out;

    float* pbuf = (float*)d_ws;                  // P floats
    float* gbuf = pbuf + PP;                     // P floats
    float* loss = gbuf + PP;                     // T floats

    void* args[] = { &feats, &labels, &params, &gWk, &gWr, &gB,
                     &gWf, &gbf, &gWi, &gbi, &out, &pbuf, &gbuf, &loss };
    hipLaunchCooperativeKernel(reinterpret_cast<const void*>(meta_kernel),
                               dim3(NB), dim3(NT), args, 0u, stream);
}

// Round 3
// 2894.327 us; speedup vs baseline: 1.1867x; 1.1867x over previous
//
#include <hip/hip_runtime.h>
#include <hip/hip_cooperative_groups.h>

namespace cg = cooperative_groups;

// Problem dims
#define DD    512
#define CC    256
#define UU    40
#define TT    16
#define BB    64
#define PP    (DD * CC)        // 131072
#define NT    512              // threads per block
#define NB    256              // blocks (1 per CU)

__device__ __forceinline__ float hsig(float x) {
    // keras hard_sigmoid: clip(0.2x + 0.5, 0, 1)
    return fminf(fmaxf(fmaf(0.2f, x, 0.5f), 0.f), 1.f);
}

__device__ __forceinline__ float ftanh(float x) {
    float xc = fminf(fmaxf(x, -15.f), 15.f);
    float e  = __expf(2.f * xc);
    return (e - 1.f) / (e + 1.f);
}

__device__ __forceinline__ float4 ld4(const float* p) {
    return *reinterpret_cast<const float4*>(p);
}

// az[0..39] = bias[GO..] + inp@Wk[:,GO..] + h@Wr[:,GO..]
// All weight addresses are wave-uniform + invariant -> scalar (s_load) path.
template <int GO>
__device__ __forceinline__ void gate_z(const float* __restrict__ Wk,   // [5][160]
                                       const float* __restrict__ Wr,   // [40][160]
                                       const float* __restrict__ Bb,   // [160]
                                       const float (&h)[UU],
                                       const float (&inp)[5],
                                       float (&az)[UU])
{
#pragma unroll
    for (int j = 0; j < 10; ++j) {
        float4 b4 = ld4(Bb + GO + 4 * j);
        az[4*j+0] = b4.x; az[4*j+1] = b4.y; az[4*j+2] = b4.z; az[4*j+3] = b4.w;
    }
#pragma unroll
    for (int k = 0; k < 5; ++k) {
        float v = inp[k];
#pragma unroll
        for (int j = 0; j < 10; ++j) {
            float4 w = ld4(Wk + k * 160 + GO + 4 * j);
            az[4*j+0] = fmaf(v, w.x, az[4*j+0]);
            az[4*j+1] = fmaf(v, w.y, az[4*j+1]);
            az[4*j+2] = fmaf(v, w.z, az[4*j+2]);
            az[4*j+3] = fmaf(v, w.w, az[4*j+3]);
        }
    }
#pragma unroll
    for (int u = 0; u < UU; ++u) {
        float hu = h[u];
#pragma unroll
        for (int j = 0; j < 10; ++j) {
            float4 w = ld4(Wr + u * 160 + GO + 4 * j);
            az[4*j+0] = fmaf(hu, w.x, az[4*j+0]);
            az[4*j+1] = fmaf(hu, w.y, az[4*j+1]);
            az[4*j+2] = fmaf(hu, w.z, az[4*j+2]);
            az[4*j+3] = fmaf(hu, w.w, az[4*j+3]);
        }
    }
}

__global__ void __launch_bounds__(NT, 2)
meta_kernel(const float* __restrict__ feats,   // [T][B][D]
            const float* __restrict__ labels,  // [T][B][C]
            const float* __restrict__ params,  // [P]
            const float* __restrict__ gWk,     // [4][5][160]
            const float* __restrict__ gWr,     // [4][40][160]
            const float* __restrict__ gB,      // [4][160]
            const float* __restrict__ gWf,     // [4][41]
            const float* __restrict__ gbf,     // [4]
            const float* __restrict__ gWi,     // [4][41]
            const float* __restrict__ gbi,     // [4]
            float* __restrict__ out,           // [P]
            float* __restrict__ pbuf,          // ws: [P]
            float* __restrict__ rbuf,          // ws: [B*C]
            float* __restrict__ loss_acc)      // ws: [T]
{
    __shared__ float sAcc[CC];    // K-split partial for phase A
    __shared__ float sRed[8];

    const int tid = threadIdx.x;
    const int blk = blockIdx.x;
    // param = blk*512 + tid ; d = param>>8 = blk*2 + (tid>>8); group bounds at d=64/192/384
    const int gi = (blk < 32) ? 0 : (blk < 96) ? 1 : (blk < 192) ? 2 : 3;

    const float* Wk = gWk + gi * 800;
    const float* Wr = gWr + gi * (UU * 160);
    const float* Bb = gB  + gi * 160;
    const float* Wf = gWf + gi * 41;
    const float* Wi = gWi + gi * 41;
    const float  bf = gbf[gi];
    const float  bi = gbi[gi];

    const int param = blk * NT + tid;
    float p = params[param];
    pbuf[param] = p;
    if (blk == 0 && tid < TT) loss_acc[tid] = 0.f;   // ws is poisoned each launch

    float h[UU], c[UU];
#pragma unroll
    for (int u = 0; u < UU; ++u) { h[u] = 0.f; c[u] = 0.f; }
    float fprev = 0.f, iprev = 0.f;

    cg::grid_group grid = cg::this_grid();

    const float negExpP = 4.5399929762484854e-05f;   // e^-10
    const float expP    = 22026.465794806718f;       // e^10

    const int dB = (blk << 1) + (tid >> 8);          // this thread's d (phase B)
    const int cB = tid & 255;                        // this thread's c

#pragma unroll 1
    for (int t = 0; t < TT; ++t) {
        grid.sync();   // pbuf (and loss zeros) visible everywhere

        // ---- Phase A (blocks 0..63): residual row b = blk, loss partial ----
        if (blk < BB) {
            const int k2 = tid >> 8;                 // K-slice 0/1
            const int cc = tid & 255;
            const float* frow = feats + (size_t)(t * BB + blk) * DD + k2 * 256;
            const float* prow = pbuf + (size_t)(k2 * 256) * CC + cc;
            float acc = 0.f;
#pragma unroll 16
            for (int d = 0; d < 256; ++d)
                acc = fmaf(frow[d], prow[d * CC], acc);   // coalesced pbuf rows
            if (k2 == 0) sAcc[cc] = acc;
            __syncthreads();
            float r2 = 0.f;
            if (k2 == 1) {
                float r = labels[(size_t)(t * BB + blk) * CC + cc] - sAcc[cc] - acc;
                rbuf[blk * CC + cc] = r;
                r2 = r * r;
            }
#pragma unroll
            for (int off = 32; off > 0; off >>= 1) r2 += __shfl_down(r2, off);
            if ((tid & 63) == 0) sRed[tid >> 6] = r2;
            __syncthreads();
            if (tid == 0) {
                float s = 0.f;
#pragma unroll
                for (int w = 0; w < 8; ++w) s += sRed[w];
                atomicAdd(&loss_acc[t], s);
            }
        }
        grid.sync();   // rbuf + loss visible

        // ---- Phase B (all blocks): grad + preprocess + LSTM + update ----
        float loss = loss_acc[t] * (1.f / 16384.f);

        // g[d,c] = -2/16384 * sum_b feats[t][b][d] * r[b][c]
        const float* fcol = feats + (size_t)t * BB * DD + dB;   // scalar per b
        const float* rrow = rbuf + cB;                          // coalesced
        float g = 0.f;
#pragma unroll 8
        for (int b = 0; b < BB; ++b)
            g = fmaf(fcol[b * DD], rrow[b * CC], g);
        g *= -1.220703125e-4f;   // -2/16384

        float ag  = fabsf(g);
        bool  m1g = ag > negExpP;
        float sgn = (g > 0.f) ? 1.f : ((g < 0.f) ? -1.f : 0.f);
        float g0  = m1g ? (logf(ag) * 0.1f) : -1.f;
        float g1  = m1g ? sgn : (expP * g);
        bool  m1l = loss > negExpP;
        float l0  = m1l ? (logf(loss) * 0.1f) : -1.f;
        float l1  = m1l ? 1.f : (expP * loss);

        float inp[5] = { p, g0, g1, l0, l1 };
        float az[UU], ig[UU];

        gate_z<0>(Wk, Wr, Bb, h, inp, az);       // i gate
#pragma unroll
        for (int j = 0; j < UU; ++j) ig[j] = hsig(az[j]);
        gate_z<40>(Wk, Wr, Bb, h, inp, az);      // f gate
#pragma unroll
        for (int j = 0; j < UU; ++j) c[j] *= hsig(az[j]);
        gate_z<80>(Wk, Wr, Bb, h, inp, az);      // cbar
#pragma unroll
        for (int j = 0; j < UU; ++j) c[j] = fmaf(ig[j], ftanh(az[j]), c[j]);
        gate_z<120>(Wk, Wr, Bb, h, inp, az);     // o gate
        float fdot = 0.f, idot = 0.f;
#pragma unroll
        for (int j = 0; j < UU; ++j) {
            float hn = hsig(az[j]) * ftanh(c[j]);
            h[j] = hn;
            fdot = fmaf(hn, Wf[j], fdot);
            idot = fmaf(hn, Wi[j], idot);
        }
        float fnew = fmaxf(fmaf(fprev, Wf[UU], fdot) + bf, 0.f);
        float inew = fmaxf(fmaf(iprev, Wi[UU], idot) + bi, 0.f);

        p = fmaf(fnew, p, -(inew * g));
        fprev = fnew; iprev = inew;
        pbuf[param] = p;
    }

    out[param] = p;
}

extern "C" void kernel_launch(void* const* d_in, const int* in_sizes, int n_in,
                              void* d_out, int out_size, void* d_ws, size_t ws_size,
                              hipStream_t stream) {
    const float* feats  = (const float*)d_in[0];
    const float* labels = (const float*)d_in[1];
    const float* params = (const float*)d_in[2];
    const float* gWk    = (const float*)d_in[3];
    const float* gWr    = (const float*)d_in[4];
    const float* gB     = (const float*)d_in[5];
    const float* gWf    = (const float*)d_in[6];
    const float* gbf    = (const float*)d_in[7];
    const float* gWi    = (const float*)d_in[8];
    const float* gbi    = (const float*)d_in[9];
    float* out  = (float*)d_out;

    float* pbuf = (float*)d_ws;                  // P floats
    float* rbuf = pbuf + PP;                     // B*C floats
    float* loss = rbuf + (BB * CC);              // T floats

    void* args[] = { &feats, &labels, &params, &gWk, &gWr, &gB,
                     &gWf, &gbf, &gWi, &gbi, &out, &pbuf, &rbuf, &loss };
    hipLaunchCooperativeKernel(reinterpret_cast<const void*>(meta_kernel),
                               dim3(NB), dim3(NT), args, 0u, stream);
}

// Round 6
// 2431.361 us; speedup vs baseline: 1.4127x; 1.1904x over previous
//
#include <hip/hip_runtime.h>
#include <hip/hip_cooperative_groups.h>

namespace cg = cooperative_groups;

#define TT 16
#define NT 512
#define NB 256

typedef _Float16 f16;
typedef f16 f16x8 __attribute__((ext_vector_type(8)));
typedef float f32x4 __attribute__((ext_vector_type(4)));

__device__ __forceinline__ float hsig(float x) {
    // keras hard_sigmoid: clip(0.2x + 0.5, 0, 1)
    return fminf(fmaxf(fmaf(0.2f, x, 0.5f), 0.f), 1.f);
}
__device__ __forceinline__ float ftanh(float x) {
    float xc = fminf(fmaxf(x, -15.f), 15.f);
    float e  = __expf(2.f * xc);
    return (e - 1.f) / (e + 1.f);
}

// X row layout (fp16, stride 56): k=0..4 inp(p,g0,g1,l0,l1), k=5..44 h[0..39],
// k=45 const 1.0 (bias row of W), k=46..55 zeros. GEMM: z^T = W^T @ X^T over K=64.
__global__ void __launch_bounds__(NT, 2)
meta_kernel(const float* __restrict__ feats,   // [T][64][512]
            const float* __restrict__ labels,  // [T][64][256]
            const float* __restrict__ params,  // [P]
            const float* __restrict__ gWk,     // [4][5][160]
            const float* __restrict__ gWr,     // [4][40][160]
            const float* __restrict__ gB,      // [4][160]
            const float* __restrict__ gWf,     // [4][41]
            const float* __restrict__ gbf,     // [4]
            const float* __restrict__ gWi,     // [4][41]
            const float* __restrict__ gbi,     // [4]
            float* __restrict__ out,           // [P]
            float* __restrict__ pbuf,          // ws [P]
            float* __restrict__ rbuf,          // ws [64*256]
            float* __restrict__ loss_acc)      // ws [T]
{
    __shared__ f16 X16[513 * 56];
    __shared__ float sRed[8];

    const int tid = threadIdx.x, blk = blockIdx.x;
    const int w = tid >> 6, lane = tid & 63, q = lane >> 4, c = lane & 15;
    const bool qhi = (q >= 2);
    const int gi = (blk < 32) ? 0 : (blk < 96) ? 1 : (blk < 192) ? 2 : 3;

    const float* Wk = gWk + gi * 800;
    const float* Wr = gWr + gi * 6400;
    const float* Bb = gB  + gi * 160;
    const float* Wf = gWf + gi * 41;
    const float* Wi = gWi + gi * 41;
    const float  bfv = gbf[gi], biv = gbi[gi];

    // ---- A-fragments: A[g][k] = W[k][g], rows of W: 0..4 Wk, 5..44 Wr, 45 bias ----
    f16x8 afr[10][2];
#pragma unroll
    for (int t = 0; t < 10; ++t)
#pragma unroll
        for (int kt = 0; kt < 2; ++kt) {
            f16x8 a;
#pragma unroll
            for (int m = 0; m < 8; ++m) {
                int k = kt * 32 + q * 8 + m;
                int g = 16 * t + c;
                float v = 0.f;
                if (k < 5)       v = Wk[k * 160 + g];
                else if (k < 45) v = Wr[(k - 5) * 160 + g];
                else if (k == 45) v = Bb[g];
                a[m] = (f16)v;
            }
            afr[t][kt] = a;
        }

    // ---- X init: zero h region + pad, bias-row input = 1.0; guard row 512 ----
    {
        f16* row = X16 + tid * 56;
        for (int k = 5; k < 56; ++k) row[k] = (f16)0.f;
        row[45] = (f16)1.0f;
        if (tid == 0) { f16* rz = X16 + 512 * 56; for (int k = 0; k < 56; ++k) rz[k] = (f16)0.f; }
    }
    if (blk == 0 && tid < TT) loss_acc[tid] = 0.f;   // ws poisoned each launch

    float pst[4], fprev[4], iprev[4], gsv[4];
    float cst[4][4][3];
#pragma unroll
    for (int ct = 0; ct < 4; ++ct) {
        int lp = w * 64 + ct * 16 + c;
        pst[ct] = params[blk * 512 + lp];
        if (q == 0) pbuf[blk * 512 + lp] = pst[ct];
        fprev[ct] = 0.f; iprev[ct] = 0.f; gsv[ct] = 0.f;
#pragma unroll
        for (int j = 0; j < 4; ++j) { cst[ct][j][0] = 0.f; cst[ct][j][1] = 0.f; cst[ct][j][2] = 0.f; }
    }
    __syncthreads();

    cg::grid_group grid = cg::this_grid();
    const float negExpP = 4.5399929762484854e-05f;   // e^-10
    const float expP    = 22026.465794806718f;       // e^10

#pragma unroll 1
    for (int ts = 0; ts < TT; ++ts) {
        grid.sync();   // pbuf (and loss zeros) visible

        // ---- Phase A: block owns C-column 'blk'; threads = 64 b x 8 k-slices ----
        {
            const int b = tid >> 3, ks = tid & 7;
            const float4* fr4 = (const float4*)(feats + ((size_t)(ts * 64 + b)) * 512 + ks * 64);
            const float*  pc  = pbuf + ks * 64 * 256 + blk;
            float acc = 0.f;
#pragma unroll
            for (int k4 = 0; k4 < 16; ++k4) {
                float4 f4 = fr4[k4];
                acc = fmaf(f4.x, pc[(k4 * 4 + 0) * 256], acc);
                acc = fmaf(f4.y, pc[(k4 * 4 + 1) * 256], acc);
                acc = fmaf(f4.z, pc[(k4 * 4 + 2) * 256], acc);
                acc = fmaf(f4.w, pc[(k4 * 4 + 3) * 256], acc);
            }
            acc += __shfl_xor(acc, 1); acc += __shfl_xor(acc, 2); acc += __shfl_xor(acc, 4);
            float r = labels[(size_t)(ts * 64 + b) * 256 + blk] - acc;
            if (ks == 0) rbuf[b * 256 + blk] = r;
            float r2 = (ks == 0) ? r * r : 0.f;
            r2 += __shfl_xor(r2, 1);  r2 += __shfl_xor(r2, 2);  r2 += __shfl_xor(r2, 4);
            r2 += __shfl_xor(r2, 8);  r2 += __shfl_xor(r2, 16); r2 += __shfl_xor(r2, 32);
            if (lane == 0) sRed[w] = r2;
            __syncthreads();
            if (tid == 0) {
                float s = 0.f;
#pragma unroll
                for (int i = 0; i < 8; ++i) s += sRed[i];
                atomicAdd(&loss_acc[ts], s);
            }
        }
        grid.sync();   // rbuf + loss visible

        // ---- Phase B ----
        float loss = loss_acc[ts] * (1.f / 16384.f);
        bool  m1l = loss > negExpP;
        float l0 = m1l ? (__logf(loss) * 0.1f) : -1.f;
        float l1 = m1l ? 1.f : (expP * loss);

        const int d = blk * 2 + (w >> 2);                 // wave-uniform
        const float* fcol = feats + (size_t)ts * 64 * 512 + d;
#pragma unroll
        for (int ct = 0; ct < 4; ++ct) {
            int lp = w * 64 + ct * 16 + c;
            int cN = (w & 3) * 64 + ct * 16 + c;
            const float* rr = rbuf + cN;
            float g = 0.f;
#pragma unroll 8
            for (int b = 0; b < 64; ++b) g = fmaf(fcol[b * 512], rr[b * 256], g);
            g *= -1.220703125e-4f;                        // -2/16384
            gsv[ct] = g;
            float ag = fabsf(g);
            bool  m1g = ag > negExpP;
            float sgn = (g > 0.f) ? 1.f : ((g < 0.f) ? -1.f : 0.f);
            float g0 = m1g ? (__logf(ag) * 0.1f) : -1.f;
            float g1 = m1g ? sgn : (expP * g);
            if (q == 0) {
                f16* xr = X16 + lp * 56;
                xr[0] = (f16)pst[ct]; xr[1] = (f16)g0; xr[2] = (f16)g1;
                xr[3] = (f16)l0;      xr[4] = (f16)l1;
            }
        }
        // Cross-lane LDS visibility: q==0 wrote inp values that all q lanes read
        // as B-fragments below. Force the ds_writes to complete (lgkmcnt drain).
        __syncthreads();

#pragma unroll
        for (int ct = 0; ct < 4; ++ct) {
            int lp = w * 64 + ct * 16 + c;
            const f16* xr = X16 + lp * 56;
            f16x8 b0 = *(const f16x8*)(xr + q * 8);
            f16x8 b1 = *(const f16x8*)(xr + 32 + q * 8);
            f32x4 acc[10];
#pragma unroll
            for (int t = 0; t < 10; ++t) {
                f32x4 z = {0.f, 0.f, 0.f, 0.f};
                z      = __builtin_amdgcn_mfma_f32_16x16x32_f16(afr[t][0], b0, z, 0, 0, 0);
                acc[t] = __builtin_amdgcn_mfma_f32_16x16x32_f16(afr[t][1], b1, z, 0, 0, 0);
            }
            float fdot = 0.f, idot = 0.f;
#pragma unroll
            for (int j = 0; j < 4; ++j) {
                int s = 4 * q + j;
                // i & cbar co-located (slots t and t+5); f & o on lane^32
                float prod0 = hsig(acc[0][j]) * ftanh(acc[5][j]);
                float prod1 = hsig(acc[1][j]) * ftanh(acc[6][j]);
                float prod2 = hsig(acc[2][j]) * ftanh(acc[7][j]);
                float f2 = hsig(acc[2][j]), f3 = hsig(acc[3][j]), f4s = hsig(acc[4][j]);
                float r2s = __shfl_xor(f2, 32), r3s = __shfl_xor(f3, 32), r4s = __shfl_xor(f4s, 32);
                float fa0 = qhi ? r3s : r2s;
                float fa1 = qhi ? r4s : r3s;
                float fa2 = r4s;                          // valid only for qlow
                float c0 = fmaf(fa0, cst[ct][j][0], prod0); cst[ct][j][0] = c0;
                float c1 = fmaf(fa1, cst[ct][j][1], prod1); cst[ct][j][1] = c1;
                float c2 = fmaf(fa2, cst[ct][j][2], prod2); cst[ct][j][2] = c2;
                float s0 = __shfl_xor(ftanh(c0), 32);
                float s1 = __shfl_xor(ftanh(c1), 32);
                float s2 = __shfl_xor(ftanh(c2), 32);
                float h7 = hsig(acc[7][j]) * s0;                    // qhi only (u=s-8)
                float h8 = hsig(acc[8][j]) * (qhi ? s1 : s0);       // u=s+8
                float h9 = hsig(acc[9][j]) * (qhi ? s2 : s1);       // u=s+24
                int u8i = s + 8, u9i = s + 24, u7i = qhi ? (s - 8) : 0;
                fdot = fmaf(h8, Wf[u8i], fdot); idot = fmaf(h8, Wi[u8i], idot);
                fdot = fmaf(h9, Wf[u9i], fdot); idot = fmaf(h9, Wi[u9i], idot);
                if (qhi) { fdot = fmaf(h7, Wf[u7i], fdot); idot = fmaf(h7, Wi[u7i], idot); }
                f16* xw = X16 + lp * 56 + 5;
                xw[u8i] = (f16)h8; xw[u9i] = (f16)h9;
                if (qhi) xw[u7i] = (f16)h7;
            }
            fdot += __shfl_xor(fdot, 16); fdot += __shfl_xor(fdot, 32);
            idot += __shfl_xor(idot, 16); idot += __shfl_xor(idot, 32);
            float fnew = fmaxf(fmaf(fprev[ct], Wf[40], fdot) + bfv, 0.f);
            float inew = fmaxf(fmaf(iprev[ct], Wi[40], idot) + biv, 0.f);
            float pn = fmaf(fnew, pst[ct], -(inew * gsv[ct]));
            pst[ct] = pn; fprev[ct] = fnew; iprev[ct] = inew;
            if (q == 0) pbuf[blk * 512 + lp] = pn;
        }
    }

#pragma unroll
    for (int ct = 0; ct < 4; ++ct)
        if (q == 0) out[blk * 512 + w * 64 + ct * 16 + c] = pst[ct];
}

extern "C" void kernel_launch(void* const* d_in, const int* in_sizes, int n_in,
                              void* d_out, int out_size, void* d_ws, size_t ws_size,
                              hipStream_t stream) {
    const float* feats  = (const float*)d_in[0];
    const float* labels = (const float*)d_in[1];
    const float* params = (const float*)d_in[2];
    const float* gWk    = (const float*)d_in[3];
    const float* gWr    = (const float*)d_in[4];
    const float* gB     = (const float*)d_in[5];
    const float* gWf    = (const float*)d_in[6];
    const float* gbf    = (const float*)d_in[7];
    const float* gWi    = (const float*)d_in[8];
    const float* gbi    = (const float*)d_in[9];
    float* out  = (float*)d_out;

    float* pbuf = (float*)d_ws;                  // 131072 floats
    float* rbuf = pbuf + 131072;                 // 64*256 floats
    float* loss = rbuf + 64 * 256;               // T floats

    void* args[] = { &feats, &labels, &params, &gWk, &gWr, &gB,
                     &gWf, &gbf, &gWi, &gbi, &out, &pbuf, &rbuf, &loss };
    hipLaunchCooperativeKernel(reinterpret_cast<const void*>(meta_kernel),
                               dim3(NB), dim3(NT), args, 0u, stream);
}

// Round 8
// 2091.136 us; speedup vs baseline: 1.6425x; 1.1627x over previous
//
#include <hip/hip_runtime.h>
#include <hip/hip_cooperative_groups.h>

namespace cg = cooperative_groups;

#define TT 16
#define NT 512
#define NB 256
#define XS 48   // X16 row stride in f16 (holds k=0..47; used 0..45)

typedef _Float16 f16;
typedef f16 f16x8 __attribute__((ext_vector_type(8)));
typedef float f32x4 __attribute__((ext_vector_type(4)));

__device__ __forceinline__ float hsig(float x) {
    // keras hard_sigmoid: clip(0.2x + 0.5, 0, 1)
    return fminf(fmaxf(fmaf(0.2f, x, 0.5f), 0.f), 1.f);
}
__device__ __forceinline__ float ftanh(float x) {
    float xc = fminf(fmaxf(x, -15.f), 15.f);
    float e  = __expf(2.f * xc);
    return (e - 1.f) / (e + 1.f);
}

// X row layout (f16, stride 48): k=0..4 inp(p,g0,g1,l0,l1), k=5..44 h[0..39],
// k=45 const 1.0 (bias row of W), k=46..47 zeros. z^T = W^T @ X^T over K=64
// (A fragments zero for k>45, so B-fragment reads of k>=46 may be any finite value).
__global__ void __launch_bounds__(NT, 2)
meta_kernel(const float* __restrict__ feats,   // [T][64][512]
            const float* __restrict__ labels,  // [T][64][256]
            const float* __restrict__ params,  // [P]
            const float* __restrict__ gWk,     // [4][5][160]
            const float* __restrict__ gWr,     // [4][40][160]
            const float* __restrict__ gB,      // [4][160]
            const float* __restrict__ gWf,     // [4][41]
            const float* __restrict__ gbf,     // [4]
            const float* __restrict__ gWi,     // [4][41]
            const float* __restrict__ gbi,     // [4]
            float* __restrict__ out,           // [P]
            float* __restrict__ pbuf,          // ws [P]
            float* __restrict__ rbuf,          // ws [64*256]
            float* __restrict__ loss_acc)      // ws [T]
{
    __shared__ f16   X16[512 * XS];   // 49152 B  (persistent LSTM input/h rows)
    __shared__ float sP[8 * 512];     // 16384 B  (phase-A pbuf stripe, XOR-swizzled)

    const int tid = threadIdx.x, blk = blockIdx.x;
    const int w = tid >> 6, lane = tid & 63, q = lane >> 4, c = lane & 15;
    const bool qhi = (q >= 2);
    const int gi = (blk < 32) ? 0 : (blk < 96) ? 1 : (blk < 192) ? 2 : 3;

    const float* Wk = gWk + gi * 800;
    const float* Wr = gWr + gi * 6400;
    const float* Bb = gB  + gi * 160;
    const float* Wf = gWf + gi * 41;
    const float* Wi = gWi + gi * 41;
    const float  bfv = gbf[gi], biv = gbi[gi];

    // ---- A-fragments: A[g][k] = W[k][g]; rows: 0..4 Wk, 5..44 Wr, 45 bias, >45 zero ----
    f16x8 afr[10][2];
#pragma unroll
    for (int t = 0; t < 10; ++t)
#pragma unroll
        for (int kt = 0; kt < 2; ++kt) {
            f16x8 a;
#pragma unroll
            for (int m = 0; m < 8; ++m) {
                int k = kt * 32 + q * 8 + m;
                int g = 16 * t + c;
                float v = 0.f;
                if (k < 5)       v = Wk[k * 160 + g];
                else if (k < 45) v = Wr[(k - 5) * 160 + g];
                else if (k == 45) v = Bb[g];
                a[m] = (f16)v;
            }
            afr[t][kt] = a;
        }

    // ---- X init: zero k=5..47, bias-row = 1.0 at k=45 ----
    {
        f16* row = X16 + tid * XS;
        for (int k = 5; k < XS; ++k) row[k] = (f16)0.f;
        row[45] = (f16)1.0f;
    }
    if (blk == 0 && tid < TT) loss_acc[tid] = 0.f;   // ws poisoned each launch

    float pst[4], fprev[4], iprev[4], gsv[4];
    float cst[4][4][3];
#pragma unroll
    for (int ct = 0; ct < 4; ++ct) {
        int lp = w * 64 + ct * 16 + c;
        pst[ct] = params[blk * 512 + lp];
        if (q == 0) pbuf[blk * 512 + lp] = pst[ct];
        fprev[ct] = 0.f; iprev[ct] = 0.f; gsv[ct] = 0.f;
#pragma unroll
        for (int j = 0; j < 4; ++j) { cst[ct][j][0] = 0.f; cst[ct][j][1] = 0.f; cst[ct][j][2] = 0.f; }
    }
    __syncthreads();

    cg::grid_group grid = cg::this_grid();
    const float negExpP = 4.5399929762484854e-05f;   // e^-10
    const float expP    = 22026.465794806718f;       // e^10

#pragma unroll 1
    for (int ts = 0; ts < TT; ++ts) {
        grid.sync();   // pbuf (and loss zeros) visible

        // ---- Phase A (blocks 0..31): forward 64x8 stripe, cols blk*8..+8 ----
        if (blk < 32) {
            const int b = tid >> 3, n = tid & 7;
            const int col = blk * 8 + n;
            // stage pbuf stripe: thread stages row k=tid, 8 cols -> swizzled sP[j][k^4j]
            {
                const float4* src = (const float4*)(pbuf + tid * 256 + blk * 8);
                float4 a0 = src[0], a1 = src[1];
                sP[0 * 512 + (tid ^  0)] = a0.x;
                sP[1 * 512 + (tid ^  4)] = a0.y;
                sP[2 * 512 + (tid ^  8)] = a0.z;
                sP[3 * 512 + (tid ^ 12)] = a0.w;
                sP[4 * 512 + (tid ^ 16)] = a1.x;
                sP[5 * 512 + (tid ^ 20)] = a1.y;
                sP[6 * 512 + (tid ^ 24)] = a1.z;
                sP[7 * 512 + (tid ^ 28)] = a1.w;
            }
            // preload feats row b: myf[jj] = feats[ts][b][jj*32 + n*4 ..+4]
            const float* frow = feats + (size_t)(ts * 64 + b) * 512;
            float4 myf[16];
#pragma unroll
            for (int jj = 0; jj < 16; ++jj)
                myf[jj] = *(const float4*)(frow + jj * 32 + n * 4);
            __syncthreads();   // sP ready

            const float* spn = sP + n * 512;
            const int swz = 4 * n;
            float acc = 0.f;
#pragma unroll
            for (int jj = 0; jj < 16; ++jj) {
#pragma unroll
                for (int src = 0; src < 8; ++src) {
                    float4 f4;
                    f4.x = __shfl(myf[jj].x, src, 8);
                    f4.y = __shfl(myf[jj].y, src, 8);
                    f4.z = __shfl(myf[jj].z, src, 8);
                    f4.w = __shfl(myf[jj].w, src, 8);
                    const float4 p4 = *(const float4*)(spn + ((jj * 32 + src * 4) ^ swz));
                    acc = fmaf(f4.x, p4.x, acc);
                    acc = fmaf(f4.y, p4.y, acc);
                    acc = fmaf(f4.z, p4.z, acc);
                    acc = fmaf(f4.w, p4.w, acc);
                }
            }
            float r = labels[(size_t)(ts * 64 + b) * 256 + col] - acc;
            rbuf[b * 256 + col] = r;
            float r2 = r * r;
            r2 += __shfl_xor(r2, 1);  r2 += __shfl_xor(r2, 2);  r2 += __shfl_xor(r2, 4);
            r2 += __shfl_xor(r2, 8);  r2 += __shfl_xor(r2, 16); r2 += __shfl_xor(r2, 32);
            if (lane == 0) atomicAdd(&loss_acc[ts], r2);
        }
        grid.sync();   // rbuf + loss visible

        // ---- Phase B (all blocks): grad + preprocess + LSTM + update ----
        float loss = loss_acc[ts] * (1.f / 16384.f);
        bool  m1l = loss > negExpP;
        float l0 = m1l ? (__logf(loss) * 0.1f) : -1.f;
        float l1 = m1l ? 1.f : (expP * loss);

        const int d = blk * 2 + (w >> 2);                 // wave-uniform
        const float* fcol = feats + (size_t)ts * 64 * 512 + d;
#pragma unroll
        for (int ct = 0; ct < 4; ++ct) {
            int lp = w * 64 + ct * 16 + c;
            int cN = (w & 3) * 64 + ct * 16 + c;
            const float* rr = rbuf + cN;
            float g = 0.f;
#pragma unroll 8
            for (int b = 0; b < 64; ++b) g = fmaf(fcol[b * 512], rr[b * 256], g);
            g *= -1.220703125e-4f;                        // -2/16384
            gsv[ct] = g;
            float ag = fabsf(g);
            bool  m1g = ag > negExpP;
            float sgn = (g > 0.f) ? 1.f : ((g < 0.f) ? -1.f : 0.f);
            float g0 = m1g ? (__logf(ag) * 0.1f) : -1.f;
            float g1 = m1g ? sgn : (expP * g);
            if (q == 0) {
                f16* xr = X16 + lp * XS;
                xr[0] = (f16)pst[ct]; xr[1] = (f16)g0; xr[2] = (f16)g1;
                xr[3] = (f16)l0;      xr[4] = (f16)l1;
            }
        }
        // Cross-lane LDS visibility: q==0 wrote inp values read by all q lanes below.
        __syncthreads();

#pragma unroll
        for (int ct = 0; ct < 4; ++ct) {
            int lp = w * 64 + ct * 16 + c;
            const f16* xr = X16 + lp * XS;
            f16x8 b0 = *(const f16x8*)(xr + q * 8);
            // b1 covers k=32..63; only k<=45 has nonzero A. q>=2 lanes (k>=48) are
            // all zero-weighted -> read harmless in-row data instead of overflowing.
            const int off1 = (q < 2) ? (32 + q * 8) : ((q - 2) * 8);
            f16x8 b1 = *(const f16x8*)(xr + off1);
            f32x4 acc[10];
#pragma unroll
            for (int t = 0; t < 10; ++t) {
                f32x4 z = {0.f, 0.f, 0.f, 0.f};
                z      = __builtin_amdgcn_mfma_f32_16x16x32_f16(afr[t][0], b0, z, 0, 0, 0);
                acc[t] = __builtin_amdgcn_mfma_f32_16x16x32_f16(afr[t][1], b1, z, 0, 0, 0);
            }
            float fdot = 0.f, idot = 0.f;
#pragma unroll
            for (int j = 0; j < 4; ++j) {
                int s = 4 * q + j;
                // i & cbar co-located (slots t and t+5); f & o on lane^32
                float prod0 = hsig(acc[0][j]) * ftanh(acc[5][j]);
                float prod1 = hsig(acc[1][j]) * ftanh(acc[6][j]);
                float prod2 = hsig(acc[2][j]) * ftanh(acc[7][j]);
                float f2 = hsig(acc[2][j]), f3 = hsig(acc[3][j]), f4s = hsig(acc[4][j]);
                float r2s = __shfl_xor(f2, 32), r3s = __shfl_xor(f3, 32), r4s = __shfl_xor(f4s, 32);
                float fa0 = qhi ? r3s : r2s;
                float fa1 = qhi ? r4s : r3s;
                float fa2 = r4s;                          // valid only for qlow
                float c0 = fmaf(fa0, cst[ct][j][0], prod0); cst[ct][j][0] = c0;
                float c1 = fmaf(fa1, cst[ct][j][1], prod1); cst[ct][j][1] = c1;
                float c2 = fmaf(fa2, cst[ct][j][2], prod2); cst[ct][j][2] = c2;
                float s0 = __shfl_xor(ftanh(c0), 32);
                float s1 = __shfl_xor(ftanh(c1), 32);
                float s2 = __shfl_xor(ftanh(c2), 32);
                float h7 = hsig(acc[7][j]) * s0;                    // qhi only (u=s-8)
                float h8 = hsig(acc[8][j]) * (qhi ? s1 : s0);       // u=s+8
                float h9 = hsig(acc[9][j]) * (qhi ? s2 : s1);       // u=s+24
                int u8i = s + 8, u9i = s + 24, u7i = qhi ? (s - 8) : 0;
                fdot = fmaf(h8, Wf[u8i], fdot); idot = fmaf(h8, Wi[u8i], idot);
                fdot = fmaf(h9, Wf[u9i], fdot); idot = fmaf(h9, Wi[u9i], idot);
                if (qhi) { fdot = fmaf(h7, Wf[u7i], fdot); idot = fmaf(h7, Wi[u7i], idot); }
                f16* xw = X16 + lp * XS + 5;
                xw[u8i] = (f16)h8; xw[u9i] = (f16)h9;
                if (qhi) xw[u7i] = (f16)h7;
            }
            fdot += __shfl_xor(fdot, 16); fdot += __shfl_xor(fdot, 32);
            idot += __shfl_xor(idot, 16); idot += __shfl_xor(idot, 32);
            float fnew = fmaxf(fmaf(fprev[ct], Wf[40], fdot) + bfv, 0.f);
            float inew = fmaxf(fmaf(iprev[ct], Wi[40], idot) + biv, 0.f);
            float pn = fmaf(fnew, pst[ct], -(inew * gsv[ct]));
            pst[ct] = pn; fprev[ct] = fnew; iprev[ct] = inew;
            if (q == 0) pbuf[blk * 512 + lp] = pn;
        }
    }

#pragma unroll
    for (int ct = 0; ct < 4; ++ct)
        if (q == 0) out[blk * 512 + w * 64 + ct * 16 + c] = pst[ct];
}

extern "C" void kernel_launch(void* const* d_in, const int* in_sizes, int n_in,
                              void* d_out, int out_size, void* d_ws, size_t ws_size,
                              hipStream_t stream) {
    const float* feats  = (const float*)d_in[0];
    const float* labels = (const float*)d_in[1];
    const float* params = (const float*)d_in[2];
    const float* gWk    = (const float*)d_in[3];
    const float* gWr    = (const float*)d_in[4];
    const float* gB     = (const float*)d_in[5];
    const float* gWf    = (const float*)d_in[6];
    const float* gbf    = (const float*)d_in[7];
    const float* gWi    = (const float*)d_in[8];
    const float* gbi    = (const float*)d_in[9];
    float* out  = (float*)d_out;

    float* pbuf = (float*)d_ws;                  // 131072 floats
    float* rbuf = pbuf + 131072;                 // 64*256 floats
    float* loss = rbuf + 64 * 256;               // T floats

    void* args[] = { &feats, &labels, &params, &gWk, &gWr, &gB,
                     &gWf, &gbf, &gWi, &gbi, &out, &pbuf, &rbuf, &loss };
    hipLaunchCooperativeKernel(reinterpret_cast<const void*>(meta_kernel),
                               dim3(NB), dim3(NT), args, 0u, stream);
}

// Round 10
// 1913.211 us; speedup vs baseline: 1.7953x; 1.0930x over previous
//
#include <hip/hip_runtime.h>
#include <hip/hip_cooperative_groups.h>

namespace cg = cooperative_groups;

#define TT 16
#define NT 512
#define NB 256
#define XS 48   // X16 row stride in f16

typedef _Float16 f16;
typedef f16 f16x2 __attribute__((ext_vector_type(2)));
typedef f16 f16x8 __attribute__((ext_vector_type(8)));
typedef float f32x4 __attribute__((ext_vector_type(4)));

__device__ __forceinline__ float hsig(float x) {
    return fminf(fmaxf(fmaf(0.2f, x, 0.5f), 0.f), 1.f);
}
__device__ __forceinline__ float ftanh(float x) {
    float xc = fminf(fmaxf(x, -15.f), 15.f);
    float e  = __expf(2.f * xc);
    return (e - 1.f) / (e + 1.f);
}

// X row layout (f16, stride 48): k=0..4 inp(p,g0,g1,l0,l1), k=5 pad(0),
// k=6..45 h[0..39] (h_u at k=6+u), k=46 const 1.0 (bias row), k=47 pad(0).
// z^T = W^T @ X^T over K=64; A zero for k=5 and k>=47.
__global__ void __launch_bounds__(NT, 2)
meta_kernel(const float* __restrict__ feats,   // [T][64][512]
            const float* __restrict__ labels,  // [T][64][256]
            const float* __restrict__ params,  // [P]
            const float* __restrict__ gWk,     // [4][5][160]
            const float* __restrict__ gWr,     // [4][40][160]
            const float* __restrict__ gB,      // [4][160]
            const float* __restrict__ gWf,     // [4][41]
            const float* __restrict__ gbf,     // [4]
            const float* __restrict__ gWi,     // [4][41]
            const float* __restrict__ gbi,     // [4]
            float* __restrict__ out,           // [P]
            float* __restrict__ pbuf,          // ws [P]
            float* __restrict__ rbuf,          // ws [64*256]
            float* __restrict__ loss_acc)      // ws [T]
{
    __shared__ __align__(16) f16   X16[512 * XS];   // 49152 B
    __shared__ __align__(16) f16   BtA[8 * 520];    //  8320 B (phase-A stripe, f16)
    __shared__ float sPart[64 * 8];                 //  2048 B (phase-A k-split partials)
    __shared__ float sRed[4];

    const int tid = threadIdx.x, blk = blockIdx.x;
    const int w = tid >> 6, lane = tid & 63, q = lane >> 4, c = lane & 15;
    const bool qhi = (q >= 2);
    const int gi = (blk < 32) ? 0 : (blk < 96) ? 1 : (blk < 192) ? 2 : 3;

    const float* Wk = gWk + gi * 800;
    const float* Wr = gWr + gi * 6400;
    const float* Bb = gB  + gi * 160;
    const float* Wf = gWf + gi * 41;
    const float* Wi = gWi + gi * 41;
    const float  bfv = gbf[gi], biv = gbi[gi];

    // ---- A-fragments: A[g][k] = W-row k, col g. k: 0..4 Wk, 5 zero, 6..45 Wr,
    // 46 bias, >=47 zero ----
    f16x8 afr[10][2];
#pragma unroll
    for (int t = 0; t < 10; ++t)
#pragma unroll
        for (int kt = 0; kt < 2; ++kt) {
            f16x8 a;
#pragma unroll
            for (int m = 0; m < 8; ++m) {
                int k = kt * 32 + q * 8 + m;
                int g = 16 * t + c;
                float v = 0.f;
                if (k < 5)                    v = Wk[k * 160 + g];
                else if (k >= 6 && k < 46)    v = Wr[(k - 6) * 160 + g];
                else if (k == 46)             v = Bb[g];
                a[m] = (f16)v;
            }
            afr[t][kt] = a;
        }

    // ---- X init: zero k=5..47, bias 1.0 at k=46 ----
    {
        f16* row = X16 + tid * XS;
        for (int k = 5; k < XS; ++k) row[k] = (f16)0.f;
        row[46] = (f16)1.0f;
    }
    if (blk == 0 && tid < TT) loss_acc[tid] = 0.f;   // ws poisoned each launch

    float pst[4], fprev[4], iprev[4];
    float cst[4][4][3];
#pragma unroll
    for (int ct = 0; ct < 4; ++ct) {
        int lp = w * 64 + ct * 16 + c;
        pst[ct] = params[blk * 512 + lp];
        if (q == 0) pbuf[blk * 512 + lp] = pst[ct];
        fprev[ct] = 0.f; iprev[ct] = 0.f;
#pragma unroll
        for (int j = 0; j < 4; ++j) { cst[ct][j][0] = 0.f; cst[ct][j][1] = 0.f; cst[ct][j][2] = 0.f; }
    }
    __syncthreads();

    cg::grid_group grid = cg::this_grid();
    const float negExpP = 4.5399929762484854e-05f;   // e^-10
    const float expP    = 22026.465794806718f;       // e^10

#pragma unroll 1
    for (int ts = 0; ts < TT; ++ts) {
        grid.sync();   // pbuf (and loss zeros) visible

        // ---- Phase A (blocks 0..31, MFMA): r[64][8] for cols blk*8..+8 ----
        if (blk < 32) {
            // stage Bt[j][d] = (f16)pbuf[d][blk*8+j]
            {
                const float4* src = (const float4*)(pbuf + tid * 256 + blk * 8);
                float4 a0 = src[0], a1 = src[1];
                BtA[0 * 520 + tid] = (f16)a0.x;
                BtA[1 * 520 + tid] = (f16)a0.y;
                BtA[2 * 520 + tid] = (f16)a0.z;
                BtA[3 * 520 + tid] = (f16)a0.w;
                BtA[4 * 520 + tid] = (f16)a1.x;
                BtA[5 * 520 + tid] = (f16)a1.y;
                BtA[6 * 520 + tid] = (f16)a1.z;
                BtA[7 * 520 + tid] = (f16)a1.w;
            }
            __syncthreads();

            const int mw = w >> 1, kw = w & 1;
            const int k0 = kw * 256;
            // A-fragments: rows b = 16*mw + c, k = k0 + kt*32 + q*8 + m
            const float* arow = feats + (size_t)(ts * 64 + mw * 16 + c) * 512 + k0 + q * 8;
            f16x8 af[8];
#pragma unroll
            for (int kt = 0; kt < 8; ++kt) {
                float4 x0 = *(const float4*)(arow + kt * 32);
                float4 x1 = *(const float4*)(arow + kt * 32 + 4);
                f16x8 a;
                a[0]=(f16)x0.x; a[1]=(f16)x0.y; a[2]=(f16)x0.z; a[3]=(f16)x0.w;
                a[4]=(f16)x1.x; a[5]=(f16)x1.y; a[6]=(f16)x1.z; a[7]=(f16)x1.w;
                af[kt] = a;
            }
            const f16* brow = BtA + (c & 7) * 520 + k0 + q * 8;
            f32x4 acc = {0.f, 0.f, 0.f, 0.f};
#pragma unroll
            for (int kt = 0; kt < 8; ++kt) {
                f16x8 bf = *(const f16x8*)(brow + kt * 32);
                acc = __builtin_amdgcn_mfma_f32_16x16x32_f16(af[kt], bf, acc, 0, 0, 0);
            }
            if (kw == 1 && c < 8) {
#pragma unroll
                for (int j = 0; j < 4; ++j)
                    sPart[(mw * 16 + 4 * q + j) * 8 + c] = acc[j];
            }
            __syncthreads();
            float rsum = 0.f;
            if (kw == 0 && c < 8) {
#pragma unroll
                for (int j = 0; j < 4; ++j) {
                    int br = mw * 16 + 4 * q + j;
                    float v = acc[j] + sPart[br * 8 + c];
                    float r = labels[(size_t)(ts * 64 + br) * 256 + blk * 8 + c] - v;
                    rbuf[br * 256 + blk * 8 + c] = r;
                    rsum = fmaf(r, r, rsum);
                }
            }
            rsum += __shfl_xor(rsum, 1);  rsum += __shfl_xor(rsum, 2);
            rsum += __shfl_xor(rsum, 4);  rsum += __shfl_xor(rsum, 8);
            rsum += __shfl_xor(rsum, 16); rsum += __shfl_xor(rsum, 32);
            if ((w & 1) == 0 && lane == 0) sRed[w >> 1] = rsum;
            __syncthreads();
            if (tid == 0)
                atomicAdd(&loss_acc[ts], sRed[0] + sRed[1] + sRed[2] + sRed[3]);
        }
        grid.sync();   // rbuf + loss visible

        // ---- Phase B (all blocks): dedup grad + preprocess + LSTM + update ----
        float loss = loss_acc[ts] * (1.f / 16384.f);
        bool  m1l = loss > negExpP;
        float l0 = m1l ? (__logf(loss) * 0.1f) : -1.f;
        float l1 = m1l ? 1.f : (expP * loss);

        // lane (q,c) computes grad of its OWN ct=q param only
        const int d = blk * 2 + (w >> 2);                 // wave-uniform
        const float* fcol = feats + (size_t)ts * 64 * 512 + d;
        const int cN = (w & 3) * 64 + q * 16 + c;         // coalesced across wave
        const float* rr = rbuf + cN;
        float g = 0.f;
#pragma unroll
        for (int bb = 0; bb < 4; ++bb) {
            float fv[16], rv[16];
#pragma unroll
            for (int b = 0; b < 16; ++b) {
                fv[b] = fcol[(bb * 16 + b) * 512];
                rv[b] = rr[(bb * 16 + b) * 256];
            }
#pragma unroll
            for (int b = 0; b < 16; ++b) g = fmaf(fv[b], rv[b], g);
        }
        g *= -1.220703125e-4f;                            // -2/16384

        float ag  = fabsf(g);
        bool  m1g = ag > negExpP;
        float sgn = (g > 0.f) ? 1.f : ((g < 0.f) ? -1.f : 0.f);
        float g0  = m1g ? (__logf(ag) * 0.1f) : -1.f;
        float g1  = m1g ? sgn : (expP * g);

        float pown = (q == 0) ? pst[0] : (q == 1) ? pst[1] : (q == 2) ? pst[2] : pst[3];
        {
            f16* xr = X16 + (w * 64 + q * 16 + c) * XS;
            xr[0] = (f16)pown; xr[1] = (f16)g0; xr[2] = (f16)g1;
            xr[3] = (f16)l0;   xr[4] = (f16)l1;
        }
        // X rows written cross-lane; drain before B-fragment reads.
        __syncthreads();

#pragma unroll
        for (int ct = 0; ct < 4; ++ct) {
            int lp = w * 64 + ct * 16 + c;
            f16* xr = X16 + lp * XS;
            f16x8 b0 = *(const f16x8*)(xr + q * 8);
            // b1 covers k=32..63; A zero for k>=47 -> q>=2 lanes read harmless in-row data
            const int off1 = (q < 2) ? (32 + q * 8) : ((q - 2) * 8);
            f16x8 b1 = *(const f16x8*)(xr + off1);
            f32x4 acc[10];
#pragma unroll
            for (int t = 0; t < 10; ++t) {
                f32x4 z = {0.f, 0.f, 0.f, 0.f};
                z      = __builtin_amdgcn_mfma_f32_16x16x32_f16(afr[t][0], b0, z, 0, 0, 0);
                acc[t] = __builtin_amdgcn_mfma_f32_16x16x32_f16(afr[t][1], b1, z, 0, 0, 0);
            }
            float fdot = 0.f, idot = 0.f;
            f16 hv8[4], hv9[4], hv7[4];
#pragma unroll
            for (int j = 0; j < 4; ++j) {
                int s = 4 * q + j;
                float prod0 = hsig(acc[0][j]) * ftanh(acc[5][j]);
                float prod1 = hsig(acc[1][j]) * ftanh(acc[6][j]);
                float prod2 = hsig(acc[2][j]) * ftanh(acc[7][j]);
                float f2 = hsig(acc[2][j]), f3 = hsig(acc[3][j]), f4s = hsig(acc[4][j]);
                float r2s = __shfl_xor(f2, 32), r3s = __shfl_xor(f3, 32), r4s = __shfl_xor(f4s, 32);
                float fa0 = qhi ? r3s : r2s;
                float fa1 = qhi ? r4s : r3s;
                float fa2 = r4s;                          // valid only for qlow
                float c0 = fmaf(fa0, cst[ct][j][0], prod0); cst[ct][j][0] = c0;
                float c1 = fmaf(fa1, cst[ct][j][1], prod1); cst[ct][j][1] = c1;
                float c2 = fmaf(fa2, cst[ct][j][2], prod2); cst[ct][j][2] = c2;
                float s0 = __shfl_xor(ftanh(c0), 32);
                float s1 = __shfl_xor(ftanh(c1), 32);
                float s2 = __shfl_xor(ftanh(c2), 32);
                float h7 = hsig(acc[7][j]) * s0;                    // qhi only (u=s-8)
                float h8 = hsig(acc[8][j]) * (qhi ? s1 : s0);       // u=s+8
                float h9 = hsig(acc[9][j]) * (qhi ? s2 : s1);       // u=s+24
                int u8i = s + 8, u9i = s + 24, u7i = qhi ? (s - 8) : 0;
                fdot = fmaf(h8, Wf[u8i], fdot); idot = fmaf(h8, Wi[u8i], idot);
                fdot = fmaf(h9, Wf[u9i], fdot); idot = fmaf(h9, Wi[u9i], idot);
                if (qhi) { fdot = fmaf(h7, Wf[u7i], fdot); idot = fmaf(h7, Wi[u7i], idot); }
                hv8[j] = (f16)h8; hv9[j] = (f16)h9; hv7[j] = (f16)h7;
            }
            // packed h writeback: h_u at k=6+u
            // u8 run (u=s+8):  k = 14+4q+j ; u9 run (u=s+24): k = 30+4q+j
            // u7 run (u=s-8, qhi): k = 4q+j-2
            {
                f16x2 p80 = {hv8[0], hv8[1]}, p81 = {hv8[2], hv8[3]};
                f16x2 p90 = {hv9[0], hv9[1]}, p91 = {hv9[2], hv9[3]};
                *(f16x2*)(xr + 14 + 4 * q) = p80;
                *(f16x2*)(xr + 16 + 4 * q) = p81;
                *(f16x2*)(xr + 30 + 4 * q) = p90;
                *(f16x2*)(xr + 32 + 4 * q) = p91;
                if (qhi) {
                    f16x2 p70 = {hv7[0], hv7[1]}, p71 = {hv7[2], hv7[3]};
                    *(f16x2*)(xr + 4 * q - 2) = p70;
                    *(f16x2*)(xr + 4 * q)     = p71;
                }
            }
            fdot += __shfl_xor(fdot, 16); fdot += __shfl_xor(fdot, 32);
            idot += __shfl_xor(idot, 16); idot += __shfl_xor(idot, 32);
            float fnew = fmaxf(fmaf(fprev[ct], Wf[40], fdot) + bfv, 0.f);
            float inew = fmaxf(fmaf(iprev[ct], Wi[40], idot) + biv, 0.f);
            float gct  = __shfl(g, ct * 16 + c);          // grad from owner lane
            float pn = fmaf(fnew, pst[ct], -(inew * gct));
            pst[ct] = pn; fprev[ct] = fnew; iprev[ct] = inew;
            if (q == 0) pbuf[blk * 512 + lp] = pn;
        }
    }

#pragma unroll
    for (int ct = 0; ct < 4; ++ct)
        if (q == 0) out[blk * 512 + w * 64 + ct * 16 + c] = pst[ct];
}

extern "C" void kernel_launch(void* const* d_in, const int* in_sizes, int n_in,
                              void* d_out, int out_size, void* d_ws, size_t ws_size,
                              hipStream_t stream) {
    const float* feats  = (const float*)d_in[0];
    const float* labels = (const float*)d_in[1];
    const float* params = (const float*)d_in[2];
    const float* gWk    = (const float*)d_in[3];
    const float* gWr    = (const float*)d_in[4];
    const float* gB     = (const float*)d_in[5];
    const float* gWf    = (const float*)d_in[6];
    const float* gbf    = (const float*)d_in[7];
    const float* gWi    = (const float*)d_in[8];
    const float* gbi    = (const float*)d_in[9];
    float* out  = (float*)d_out;

    float* pbuf = (float*)d_ws;                  // 131072 floats
    float* rbuf = pbuf + 131072;                 // 64*256 floats
    float* loss = rbuf + 64 * 256;               // T floats

    void* args[] = { &feats, &labels, &params, &gWk, &gWr, &gB,
                     &gWf, &gbf, &gWi, &gbi, &out, &pbuf, &rbuf, &loss };
    hipLaunchCooperativeKernel(reinterpret_cast<const void*>(meta_kernel),
                               dim3(NB), dim3(NT), args, 0u, stream);
}

// Round 11
// 956.090 us; speedup vs baseline: 3.5925x; 2.0011x over previous
//
#include <hip/hip_runtime.h>
#include <hip/hip_cooperative_groups.h>

namespace cg = cooperative_groups;

#define TT 16
#define NT 512
#define NB 256
#define XS 48   // X16 row stride in f16

typedef _Float16 f16;
typedef f16 f16x2 __attribute__((ext_vector_type(2)));
typedef f16 f16x8 __attribute__((ext_vector_type(8)));
typedef float f32x4 __attribute__((ext_vector_type(4)));

__device__ __forceinline__ float hsig(float x) {
    return fminf(fmaxf(fmaf(0.2f, x, 0.5f), 0.f), 1.f);
}
__device__ __forceinline__ float ftanh(float x) {
    float xc = fminf(fmaxf(x, -15.f), 15.f);
    float e  = __expf(2.f * xc);
    return (e - 1.f) / (e + 1.f);
}

// Block 'blk' owns C-column blk: params p(d) = d*256+blk, d=0..511.
// Wave w owns d in [64w, 64w+64) -> LSTM group is wave-uniform:
//   w=0 -> g0 (d<64); w=1,2 -> g1; w=3..5 -> g2; w=6,7 -> g3.
// X row layout (f16, stride 48): k=0..4 inp(p,g0,g1,l0,l1), k=5 pad(0),
// k=6..45 h[0..39] (h_u at k=6+u), k=46 const 1.0 (bias), k=47 pad(0).
// sPcol: P column in LDS, padded addr S(d) = d + 4*(d>>6) (bank-spread, 16B-aligned).
__global__ void __launch_bounds__(NT, 2)
meta_kernel(const float* __restrict__ feats,   // [T][64][512]
            const float* __restrict__ labels,  // [T][64][256]
            const float* __restrict__ params,  // [P]
            const float* __restrict__ gWk,     // [4][5][160]
            const float* __restrict__ gWr,     // [4][40][160]
            const float* __restrict__ gB,      // [4][160]
            const float* __restrict__ gWf,     // [4][41]
            const float* __restrict__ gbf,     // [4]
            const float* __restrict__ gWi,     // [4][41]
            const float* __restrict__ gbi,     // [4]
            float* __restrict__ out,           // [P]
            float* __restrict__ loss_acc)      // ws [T], pre-zeroed by memset
{
    __shared__ __align__(16) f16   X16[512 * XS];   // 49152 B
    __shared__ __align__(16) float sPcol[544];      //  2176 B
    __shared__ float sR[64];
    __shared__ float sRed[8];

    const int tid = threadIdx.x, blk = blockIdx.x;
    const int w = tid >> 6, lane = tid & 63, q = lane >> 4, c = lane & 15;
    const bool qhi = (q >= 2);
    const int gw = (w == 0) ? 0 : (w < 3) ? 1 : (w < 6) ? 2 : 3;   // wave's group

    const float* Wk = gWk + gw * 800;
    const float* Wr = gWr + gw * 6400;
    const float* Bb = gB  + gw * 160;
    const float* Wf = gWf + gw * 41;
    const float* Wi = gWi + gw * 41;
    const float  bfv = gbf[gw], biv = gbi[gw];

    // ---- A-fragments: A[g][k] = W-row k, col g. k: 0..4 Wk, 5 zero, 6..45 Wr,
    // 46 bias, >=47 zero ----
    f16x8 afr[10][2];
#pragma unroll
    for (int t = 0; t < 10; ++t)
#pragma unroll
        for (int kt = 0; kt < 2; ++kt) {
            f16x8 a;
#pragma unroll
            for (int m = 0; m < 8; ++m) {
                int k = kt * 32 + q * 8 + m;
                int g = 16 * t + c;
                float v = 0.f;
                if (k < 5)                    v = Wk[k * 160 + g];
                else if (k >= 6 && k < 46)    v = Wr[(k - 6) * 160 + g];
                else if (k == 46)             v = Bb[g];
                a[m] = (f16)v;
            }
            afr[t][kt] = a;
        }

    // ---- X init: zero k=5..47, bias 1.0 at k=46 ----
    {
        f16* row = X16 + tid * XS;
        for (int k = 5; k < XS; ++k) row[k] = (f16)0.f;
        row[46] = (f16)1.0f;
    }

    float pst[4], fprev[4], iprev[4];
    float cst[4][4][3];
#pragma unroll
    for (int ct = 0; ct < 4; ++ct) {
        const int d = w * 64 + ct * 16 + c;
        pst[ct] = params[d * 256 + blk];
        if (q == 0) sPcol[d + 4 * w] = pst[ct];     // S(d) = d + 4*(d>>6), d>>6 == w
        fprev[ct] = 0.f; iprev[ct] = 0.f;
#pragma unroll
        for (int j = 0; j < 4; ++j) { cst[ct][j][0] = 0.f; cst[ct][j][1] = 0.f; cst[ct][j][2] = 0.f; }
    }
    __syncthreads();

    cg::grid_group grid = cg::this_grid();
    const float negExpP = 4.5399929762484854e-05f;   // e^-10
    const float expP    = 22026.465794806718f;       // e^10

#pragma unroll 1
    for (int ts = 0; ts < TT; ++ts) {
        // ---- Phase A (block-local): r[b] = y[b,blk] - f[b,:]·P[:,blk] ----
        const int b = tid >> 3, ks = tid & 7;
        const float* frow = feats + (size_t)(ts * 64 + b) * 512;
        float acc = 0.f;
#pragma unroll
        for (int i = 0; i < 16; ++i) {
            const float4 f4 = *(const float4*)(frow + i * 32 + ks * 4);
            const float4 p4 = *(const float4*)(sPcol + i * 32 + ks * 4 + 4 * (i >> 1));
            acc = fmaf(f4.x, p4.x, acc);
            acc = fmaf(f4.y, p4.y, acc);
            acc = fmaf(f4.z, p4.z, acc);
            acc = fmaf(f4.w, p4.w, acc);
        }
        acc += __shfl_xor(acc, 1); acc += __shfl_xor(acc, 2); acc += __shfl_xor(acc, 4);
        float r = labels[(size_t)(ts * 64 + b) * 256 + blk] - acc;
        if (ks == 0) sR[b] = r;
        float r2 = (ks == 0) ? r * r : 0.f;
        r2 += __shfl_xor(r2, 1);  r2 += __shfl_xor(r2, 2);  r2 += __shfl_xor(r2, 4);
        r2 += __shfl_xor(r2, 8);  r2 += __shfl_xor(r2, 16); r2 += __shfl_xor(r2, 32);
        if (lane == 0) sRed[w] = r2;
        __syncthreads();   // sR + sRed ready
        if (tid == 0) {
            float s = 0.f;
#pragma unroll
            for (int i = 0; i < 8; ++i) s += sRed[i];
            atomicAdd(&loss_acc[ts], s);
        }

        // ---- grad for OWN param d = w*64+q*16+c (independent of loss) ----
        const int dg = w * 64 + q * 16 + c;
        const float* fg = feats + (size_t)ts * 64 * 512 + dg;
        float g = 0.f;
#pragma unroll 16
        for (int b2 = 0; b2 < 64; ++b2) g = fmaf(fg[b2 * 512], sR[b2], g);
        g *= -1.220703125e-4f;                        // -2/16384

        grid.sync();   // all loss partials in

        // ---- Phase B (block-local LSTM) ----
        float loss = loss_acc[ts] * (1.f / 16384.f);
        bool  m1l = loss > negExpP;
        float l0 = m1l ? (__logf(loss) * 0.1f) : -1.f;
        float l1 = m1l ? 1.f : (expP * loss);

        float ag  = fabsf(g);
        bool  m1g = ag > negExpP;
        float sgn = (g > 0.f) ? 1.f : ((g < 0.f) ? -1.f : 0.f);
        float g0  = m1g ? (__logf(ag) * 0.1f) : -1.f;
        float g1  = m1g ? sgn : (expP * g);

        float pown = (q == 0) ? pst[0] : (q == 1) ? pst[1] : (q == 2) ? pst[2] : pst[3];
        {
            f16* xr = X16 + (w * 64 + q * 16 + c) * XS;
            xr[0] = (f16)pown; xr[1] = (f16)g0; xr[2] = (f16)g1;
            xr[3] = (f16)l0;   xr[4] = (f16)l1;
        }
        __syncthreads();   // X rows written cross-lane; drain before B-fragment reads

#pragma unroll
        for (int ct = 0; ct < 4; ++ct) {
            const int lp = w * 64 + ct * 16 + c;
            f16* xr = X16 + lp * XS;
            f16x8 b0 = *(const f16x8*)(xr + q * 8);
            // b1 covers k=32..63; A zero for k>=47 -> q>=2 lanes read harmless in-row data
            const int off1 = (q < 2) ? (32 + q * 8) : ((q - 2) * 8);
            f16x8 b1 = *(const f16x8*)(xr + off1);
            f32x4 acc2[10];
#pragma unroll
            for (int t = 0; t < 10; ++t) {
                f32x4 z = {0.f, 0.f, 0.f, 0.f};
                z       = __builtin_amdgcn_mfma_f32_16x16x32_f16(afr[t][0], b0, z, 0, 0, 0);
                acc2[t] = __builtin_amdgcn_mfma_f32_16x16x32_f16(afr[t][1], b1, z, 0, 0, 0);
            }
            float fdot = 0.f, idot = 0.f;
            f16 hv8[4], hv9[4], hv7[4];
#pragma unroll
            for (int j = 0; j < 4; ++j) {
                int s = 4 * q + j;
                float prod0 = hsig(acc2[0][j]) * ftanh(acc2[5][j]);
                float prod1 = hsig(acc2[1][j]) * ftanh(acc2[6][j]);
                float prod2 = hsig(acc2[2][j]) * ftanh(acc2[7][j]);
                float f2 = hsig(acc2[2][j]), f3 = hsig(acc2[3][j]), f4s = hsig(acc2[4][j]);
                float r2s = __shfl_xor(f2, 32), r3s = __shfl_xor(f3, 32), r4s = __shfl_xor(f4s, 32);
                float fa0 = qhi ? r3s : r2s;
                float fa1 = qhi ? r4s : r3s;
                float fa2 = r4s;                          // valid only for qlow
                float c0 = fmaf(fa0, cst[ct][j][0], prod0); cst[ct][j][0] = c0;
                float c1 = fmaf(fa1, cst[ct][j][1], prod1); cst[ct][j][1] = c1;
                float c2 = fmaf(fa2, cst[ct][j][2], prod2); cst[ct][j][2] = c2;
                float s0 = __shfl_xor(ftanh(c0), 32);
                float s1 = __shfl_xor(ftanh(c1), 32);
                float s2 = __shfl_xor(ftanh(c2), 32);
                float h7 = hsig(acc2[7][j]) * s0;                   // qhi only (u=s-8)
                float h8 = hsig(acc2[8][j]) * (qhi ? s1 : s0);      // u=s+8
                float h9 = hsig(acc2[9][j]) * (qhi ? s2 : s1);      // u=s+24
                int u8i = s + 8, u9i = s + 24, u7i = qhi ? (s - 8) : 0;
                fdot = fmaf(h8, Wf[u8i], fdot); idot = fmaf(h8, Wi[u8i], idot);
                fdot = fmaf(h9, Wf[u9i], fdot); idot = fmaf(h9, Wi[u9i], idot);
                if (qhi) { fdot = fmaf(h7, Wf[u7i], fdot); idot = fmaf(h7, Wi[u7i], idot); }
                hv8[j] = (f16)h8; hv9[j] = (f16)h9; hv7[j] = (f16)h7;
            }
            // packed h writeback: h_u at k=6+u
            // u8 (u=s+8): k=14+4q+j ; u9 (u=s+24): k=30+4q+j ; u7 (u=s-8, qhi): k=4q+j-2
            {
                f16x2 p80 = {hv8[0], hv8[1]}, p81 = {hv8[2], hv8[3]};
                f16x2 p90 = {hv9[0], hv9[1]}, p91 = {hv9[2], hv9[3]};
                *(f16x2*)(xr + 14 + 4 * q) = p80;
                *(f16x2*)(xr + 16 + 4 * q) = p81;
                *(f16x2*)(xr + 30 + 4 * q) = p90;
                *(f16x2*)(xr + 32 + 4 * q) = p91;
                if (qhi) {
                    f16x2 p70 = {hv7[0], hv7[1]}, p71 = {hv7[2], hv7[3]};
                    *(f16x2*)(xr + 4 * q - 2) = p70;
                    *(f16x2*)(xr + 4 * q)     = p71;
                }
            }
            fdot += __shfl_xor(fdot, 16); fdot += __shfl_xor(fdot, 32);
            idot += __shfl_xor(idot, 16); idot += __shfl_xor(idot, 32);
            float fnew = fmaxf(fmaf(fprev[ct], Wf[40], fdot) + bfv, 0.f);
            float inew = fmaxf(fmaf(iprev[ct], Wi[40], idot) + biv, 0.f);
            float gct  = __shfl(g, ct * 16 + c);          // grad from owner lane
            float pn = fmaf(fnew, pst[ct], -(inew * gct));
            pst[ct] = pn; fprev[ct] = fnew; iprev[ct] = inew;
            if (q == 0) sPcol[lp + 4 * w] = pn;           // next step's forward input
        }
        __syncthreads();   // sPcol + X16 settled before next forward
    }

#pragma unroll
    for (int ct = 0; ct < 4; ++ct)
        if (q == 0) out[(w * 64 + ct * 16 + c) * 256 + blk] = pst[ct];
}

extern "C" void kernel_launch(void* const* d_in, const int* in_sizes, int n_in,
                              void* d_out, int out_size, void* d_ws, size_t ws_size,
                              hipStream_t stream) {
    const float* feats  = (const float*)d_in[0];
    const float* labels = (const float*)d_in[1];
    const float* params = (const float*)d_in[2];
    const float* gWk    = (const float*)d_in[3];
    const float* gWr    = (const float*)d_in[4];
    const float* gB     = (const float*)d_in[5];
    const float* gWf    = (const float*)d_in[6];
    const float* gbf    = (const float*)d_in[7];
    const float* gWi    = (const float*)d_in[8];
    const float* gbi    = (const float*)d_in[9];
    float* out  = (float*)d_out;

    float* loss = (float*)d_ws;                  // [TT] loss accumulators
    hipMemsetAsync(loss, 0, TT * sizeof(float), stream);   // stream-ordered, capture-safe

    void* args[] = { &feats, &labels, &params, &gWk, &gWr, &gB,
                     &gWf, &gbf, &gWi, &gbi, &out, &loss };
    hipLaunchCooperativeKernel(reinterpret_cast<const void*>(meta_kernel),
                               dim3(NB), dim3(NT), args, 0u, stream);
}

// Round 12
// 766.271 us; speedup vs baseline: 4.4824x; 1.2477x over previous
//
#include <hip/hip_runtime.h>
#include <hip/hip_cooperative_groups.h>

#define TT 16
#define NT 512
#define NB 256
#define XS 56   // X16 row stride in f16 (112 B -> only 2-way bank aliasing)

typedef _Float16 f16;
typedef f16 f16x2 __attribute__((ext_vector_type(2)));
typedef f16 f16x8 __attribute__((ext_vector_type(8)));
typedef float f32x4 __attribute__((ext_vector_type(4)));

__device__ __forceinline__ float hsig(float x) {
    return fminf(fmaxf(fmaf(0.2f, x, 0.5f), 0.f), 1.f);
}
__device__ __forceinline__ float ftanh(float x) {
    float xc = fminf(fmaxf(x, -15.f), 15.f);
    float e  = __expf(2.f * xc);
    return (e - 1.f) * __builtin_amdgcn_rcpf(e + 1.f);   // ~2.4e-7 rel err
}

// Block 'blk' owns C-column blk: params p(d) = d*256+blk, d=0..511.
// Wave w owns d in [64w, 64w+64) -> LSTM group wave-uniform: w=0->g0; w<3->g1; w<6->g2; else g3.
// X row (f16, stride 56): k=0..4 inp(p,g0,g1,l0,l1), k=5 pad, k=6..45 h[0..39] (h_u at 6+u),
// k=46 const 1.0 (bias), k=47..55 pad(0). z^T = W^T @ X^T over K=64; A zero for k=5, k>=47.
// Cross-block data: ONLY the scalar loss (one-sided barrier on cnt_acc[ts]).
__global__ void __launch_bounds__(NT, 2)
meta_kernel(const float* __restrict__ feats,   // [T][64][512]
            const float* __restrict__ labels,  // [T][64][256]
            const float* __restrict__ params,  // [P]
            const float* __restrict__ gWk,     // [4][5][160]
            const float* __restrict__ gWr,     // [4][40][160]
            const float* __restrict__ gB,      // [4][160]
            const float* __restrict__ gWf,     // [4][41]
            const float* __restrict__ gbf,     // [4]
            const float* __restrict__ gWi,     // [4][41]
            const float* __restrict__ gbi,     // [4]
            float* __restrict__ out,           // [P]
            float* __restrict__ loss_acc,      // ws [T], pre-zeroed
            unsigned int* __restrict__ cnt_acc)// ws [T], pre-zeroed
{
    __shared__ __align__(16) f16   X16[512 * XS];   // 57344 B
    __shared__ __align__(16) float sPcol[544];      //  2176 B
    __shared__ float sR[64];
    __shared__ float sRed[8];
    __shared__ float sLoss;

    const int tid = threadIdx.x, blk = blockIdx.x;
    const int w = tid >> 6, lane = tid & 63, q = lane >> 4, c = lane & 15;
    const bool qhi = (q >= 2);
    const int gw = (w == 0) ? 0 : (w < 3) ? 1 : (w < 6) ? 2 : 3;   // wave's group

    const float* Wk = gWk + gw * 800;
    const float* Wr = gWr + gw * 6400;
    const float* Bb = gB  + gw * 160;
    const float* Wf = gWf + gw * 41;
    const float* Wi = gWi + gw * 41;
    const float  bfv = gbf[gw], biv = gbi[gw];

    // ---- A-fragments: A[g][k] = W-row k, col g. k: 0..4 Wk, 5 zero, 6..45 Wr,
    // 46 bias, >=47 zero ----
    f16x8 afr[10][2];
#pragma unroll
    for (int t = 0; t < 10; ++t)
#pragma unroll
        for (int kt = 0; kt < 2; ++kt) {
            f16x8 a;
#pragma unroll
            for (int m = 0; m < 8; ++m) {
                int k = kt * 32 + q * 8 + m;
                int g = 16 * t + c;
                float v = 0.f;
                if (k < 5)                    v = Wk[k * 160 + g];
                else if (k >= 6 && k < 46)    v = Wr[(k - 6) * 160 + g];
                else if (k == 46)             v = Bb[g];
                a[m] = (f16)v;
            }
            afr[t][kt] = a;
        }

    // ---- X init: zero k=5..55, bias 1.0 at k=46 ----
    {
        f16* row = X16 + tid * XS;
        for (int k = 5; k < XS; ++k) row[k] = (f16)0.f;
        row[46] = (f16)1.0f;
    }

    float pst[4], fprev[4], iprev[4];
    float cst[4][4][3];
#pragma unroll
    for (int ct = 0; ct < 4; ++ct) {
        const int d = w * 64 + ct * 16 + c;
        pst[ct] = params[d * 256 + blk];
        if (q == 0) sPcol[d + 4 * w] = pst[ct];     // S(d) = d + 4*(d>>6)
        fprev[ct] = 0.f; iprev[ct] = 0.f;
#pragma unroll
        for (int j = 0; j < 4; ++j) { cst[ct][j][0] = 0.f; cst[ct][j][1] = 0.f; cst[ct][j][2] = 0.f; }
    }
    __syncthreads();

    const float negExpP = 4.5399929762484854e-05f;   // e^-10
    const float expP    = 22026.465794806718f;       // e^10

#pragma unroll 1
    for (int ts = 0; ts < TT; ++ts) {
        // ---- Phase A (block-local): r[b] = y[b,blk] - f[b,:]·P[:,blk] ----
        const int b = tid >> 3, ks = tid & 7;
        const float* frow = feats + (size_t)(ts * 64 + b) * 512;
        float acc = 0.f;
#pragma unroll
        for (int i = 0; i < 16; ++i) {
            const float4 f4 = *(const float4*)(frow + i * 32 + ks * 4);
            const float4 p4 = *(const float4*)(sPcol + i * 32 + ks * 4 + 4 * (i >> 1));
            acc = fmaf(f4.x, p4.x, acc);
            acc = fmaf(f4.y, p4.y, acc);
            acc = fmaf(f4.z, p4.z, acc);
            acc = fmaf(f4.w, p4.w, acc);
        }
        acc += __shfl_xor(acc, 1); acc += __shfl_xor(acc, 2); acc += __shfl_xor(acc, 4);
        float r = labels[(size_t)(ts * 64 + b) * 256 + blk] - acc;
        if (ks == 0) sR[b] = r;
        float r2 = (ks == 0) ? r * r : 0.f;
        r2 += __shfl_xor(r2, 1);  r2 += __shfl_xor(r2, 2);  r2 += __shfl_xor(r2, 4);
        r2 += __shfl_xor(r2, 8);  r2 += __shfl_xor(r2, 16); r2 += __shfl_xor(r2, 32);
        if (lane == 0) sRed[w] = r2;
        __syncthreads();   // sR + sRed ready
        if (tid == 0) {
            float s = ((sRed[0] + sRed[1]) + (sRed[2] + sRed[3]))
                    + ((sRed[4] + sRed[5]) + (sRed[6] + sRed[7]));
            atomicAdd(&loss_acc[ts], s);    // device-scope RMW (coherent point)
            __hip_atomic_fetch_add(&cnt_acc[ts], 1u,
                                   __ATOMIC_RELEASE, __HIP_MEMORY_SCOPE_AGENT);
        }

        // ---- grad for OWN param d = w*64+q*16+c (needs only sR; overlaps barrier) ----
        const int dg = w * 64 + q * 16 + c;
        const float* fg = feats + (size_t)ts * 64 * 512 + dg;
        float ga = 0.f, gb2 = 0.f, gc2 = 0.f, gd2 = 0.f;
#pragma unroll
        for (int b2 = 0; b2 < 64; b2 += 4) {
            ga  = fmaf(fg[(b2 + 0) * 512], sR[b2 + 0], ga);
            gb2 = fmaf(fg[(b2 + 1) * 512], sR[b2 + 1], gb2);
            gc2 = fmaf(fg[(b2 + 2) * 512], sR[b2 + 2], gc2);
            gd2 = fmaf(fg[(b2 + 3) * 512], sR[b2 + 3], gd2);
        }
        float g = ((ga + gb2) + (gc2 + gd2)) * -1.220703125e-4f;   // -2/16384

        // ---- one-sided loss barrier: wait for all 256 partials ----
        if (tid == 0) {
            while (__hip_atomic_load(&cnt_acc[ts],
                                     __ATOMIC_ACQUIRE, __HIP_MEMORY_SCOPE_AGENT) < NB)
                __builtin_amdgcn_s_sleep(2);
            sLoss = atomicAdd(&loss_acc[ts], 0.f);   // coherent read of final sum
        }
        __syncthreads();

        // ---- Phase B (block-local LSTM) ----
        float loss = sLoss * (1.f / 16384.f);
        bool  m1l = loss > negExpP;
        float l0 = m1l ? (__logf(loss) * 0.1f) : -1.f;
        float l1 = m1l ? 1.f : (expP * loss);

        float ag  = fabsf(g);
        bool  m1g = ag > negExpP;
        float sgn = (g > 0.f) ? 1.f : ((g < 0.f) ? -1.f : 0.f);
        float g0  = m1g ? (__logf(ag) * 0.1f) : -1.f;
        float g1  = m1g ? sgn : (expP * g);

        float pown = (q == 0) ? pst[0] : (q == 1) ? pst[1] : (q == 2) ? pst[2] : pst[3];
        {
            f16* xr = X16 + (w * 64 + q * 16 + c) * XS;
            xr[0] = (f16)pown; xr[1] = (f16)g0; xr[2] = (f16)g1;
            xr[3] = (f16)l0;   xr[4] = (f16)l1;
        }
        __syncthreads();   // X rows written cross-lane; drain before B-fragment reads

#pragma unroll
        for (int ct = 0; ct < 4; ++ct) {
            const int lp = w * 64 + ct * 16 + c;
            f16* xr = X16 + lp * XS;
            f16x8 b0 = *(const f16x8*)(xr + q * 8);
            // b1 covers k=32..63; A zero for k>=47 -> q>=2 lanes read harmless in-row data
            const int off1 = (q < 2) ? (32 + q * 8) : ((q - 2) * 8);
            f16x8 b1 = *(const f16x8*)(xr + off1);
            f32x4 acc2[10];
#pragma unroll
            for (int t = 0; t < 10; ++t) {
                f32x4 z = {0.f, 0.f, 0.f, 0.f};
                z       = __builtin_amdgcn_mfma_f32_16x16x32_f16(afr[t][0], b0, z, 0, 0, 0);
                acc2[t] = __builtin_amdgcn_mfma_f32_16x16x32_f16(afr[t][1], b1, z, 0, 0, 0);
            }
            float fdot = 0.f, idot = 0.f;
            f16 hv8[4], hv9[4], hv7[4];
#pragma unroll
            for (int j = 0; j < 4; ++j) {
                int s = 4 * q + j;
                float prod0 = hsig(acc2[0][j]) * ftanh(acc2[5][j]);
                float prod1 = hsig(acc2[1][j]) * ftanh(acc2[6][j]);
                float prod2 = hsig(acc2[2][j]) * ftanh(acc2[7][j]);
                float f2 = hsig(acc2[2][j]), f3 = hsig(acc2[3][j]), f4s = hsig(acc2[4][j]);
                float r2s = __shfl_xor(f2, 32), r3s = __shfl_xor(f3, 32), r4s = __shfl_xor(f4s, 32);
                float fa0 = qhi ? r3s : r2s;
                float fa1 = qhi ? r4s : r3s;
                float fa2 = r4s;                          // valid only for qlow
                float c0 = fmaf(fa0, cst[ct][j][0], prod0); cst[ct][j][0] = c0;
                float c1 = fmaf(fa1, cst[ct][j][1], prod1); cst[ct][j][1] = c1;
                float c2 = fmaf(fa2, cst[ct][j][2], prod2); cst[ct][j][2] = c2;
                float s0 = __shfl_xor(ftanh(c0), 32);
                float s1 = __shfl_xor(ftanh(c1), 32);
                float s2 = __shfl_xor(ftanh(c2), 32);
                float h7 = hsig(acc2[7][j]) * s0;                   // qhi only (u=s-8)
                float h8 = hsig(acc2[8][j]) * (qhi ? s1 : s0);      // u=s+8
                float h9 = hsig(acc2[9][j]) * (qhi ? s2 : s1);      // u=s+24
                int u8i = s + 8, u9i = s + 24, u7i = qhi ? (s - 8) : 0;
                fdot = fmaf(h8, Wf[u8i], fdot); idot = fmaf(h8, Wi[u8i], idot);
                fdot = fmaf(h9, Wf[u9i], fdot); idot = fmaf(h9, Wi[u9i], idot);
                if (qhi) { fdot = fmaf(h7, Wf[u7i], fdot); idot = fmaf(h7, Wi[u7i], idot); }
                hv8[j] = (f16)h8; hv9[j] = (f16)h9; hv7[j] = (f16)h7;
            }
            // packed h writeback: h_u at k=6+u
            // u8 (u=s+8): k=14+4q+j ; u9 (u=s+24): k=30+4q+j ; u7 (u=s-8, qhi): k=4q+j-2
            {
                f16x2 p80 = {hv8[0], hv8[1]}, p81 = {hv8[2], hv8[3]};
                f16x2 p90 = {hv9[0], hv9[1]}, p91 = {hv9[2], hv9[3]};
                *(f16x2*)(xr + 14 + 4 * q) = p80;
                *(f16x2*)(xr + 16 + 4 * q) = p81;
                *(f16x2*)(xr + 30 + 4 * q) = p90;
                *(f16x2*)(xr + 32 + 4 * q) = p91;
                if (qhi) {
                    f16x2 p70 = {hv7[0], hv7[1]}, p71 = {hv7[2], hv7[3]};
                    *(f16x2*)(xr + 4 * q - 2) = p70;
                    *(f16x2*)(xr + 4 * q)     = p71;
                }
            }
            fdot += __shfl_xor(fdot, 16); fdot += __shfl_xor(fdot, 32);
            idot += __shfl_xor(idot, 16); idot += __shfl_xor(idot, 32);
            float fnew = fmaxf(fmaf(fprev[ct], Wf[40], fdot) + bfv, 0.f);
            float inew = fmaxf(fmaf(iprev[ct], Wi[40], idot) + biv, 0.f);
            float gct  = __shfl(g, ct * 16 + c);          // grad from owner lane
            float pn = fmaf(fnew, pst[ct], -(inew * gct));
            pst[ct] = pn; fprev[ct] = fnew; iprev[ct] = inew;
            if (q == 0) sPcol[lp + 4 * w] = pn;           // next step's forward input
        }
        __syncthreads();   // sPcol + X16 settled before next forward
    }

#pragma unroll
    for (int ct = 0; ct < 4; ++ct)
        if (q == 0) out[(w * 64 + ct * 16 + c) * 256 + blk] = pst[ct];
}

extern "C" void kernel_launch(void* const* d_in, const int* in_sizes, int n_in,
                              void* d_out, int out_size, void* d_ws, size_t ws_size,
                              hipStream_t stream) {
    const float* feats  = (const float*)d_in[0];
    const float* labels = (const float*)d_in[1];
    const float* params = (const float*)d_in[2];
    const float* gWk    = (const float*)d_in[3];
    const float* gWr    = (const float*)d_in[4];
    const float* gB     = (const float*)d_in[5];
    const float* gWf    = (const float*)d_in[6];
    const float* gbf    = (const float*)d_in[7];
    const float* gWi    = (const float*)d_in[8];
    const float* gbi    = (const float*)d_in[9];
    float* out  = (float*)d_out;

    float*        loss = (float*)d_ws;           // [TT]
    unsigned int* cnt  = (unsigned int*)(loss + TT);  // [TT]
    hipMemsetAsync(d_ws, 0, 2 * TT * sizeof(float), stream);   // stream-ordered, capture-safe

    void* args[] = { &feats, &labels, &params, &gWk, &gWr, &gB,
                     &gWf, &gbf, &gWi, &gbi, &out, &loss, &cnt };
    hipLaunchCooperativeKernel(reinterpret_cast<const void*>(meta_kernel),
                               dim3(NB), dim3(NT), args, 0u, stream);
}